// Round 11
// baseline (290.495 us; speedup 1.0000x reference)
//
#include <hip/hip_runtime.h>

#define NN 50000
#define NE 800000
#define D  128

typedef _Float16 f16;
typedef _Float16 f16x4 __attribute__((ext_vector_type(4)));
typedef _Float16 f16x8 __attribute__((ext_vector_type(8)));
typedef float f32x4 __attribute__((ext_vector_type(4)));
typedef float f32x2 __attribute__((ext_vector_type(2)));
typedef unsigned short u16;
typedef unsigned int u32;
typedef unsigned char u8;

#define NB   64      // histogram blocks
#define ECH  12500   // NE / NB
#define NHW  12500   // NN/4 u8-packed hist words per block

// ---------------- fused prep + histogram ----------------
// blocks [0,64): per-block LDS histogram of its 12500 edges (u8 x4 packed in
//   u32, 50 KB LDS). LDS atomicAdd return = local rank.
// [64, 64+1563): x -> xf (f16) + xf8 (fp8); [1627, 1651): 6 weight mats.
// The 64 hist blocks occupy 64 CUs while converts fill the rest.
__global__ __launch_bounds__(1024) void prep_hist(
    const float* __restrict__ x, f16* __restrict__ xf, u8* __restrict__ xf8,
    const float* w0, const float* w1, const float* w2,
    const float* w3, const float* w4, const float* w5,
    f16* d0, f16* d1, f16* d2, f16* d3, f16* d4, f16* d5,
    const int* __restrict__ erow, u32* __restrict__ histw,
    u16* __restrict__ lrank, int* __restrict__ cursor) {
    __shared__ u32 lh[NHW];   // 50 KB
    int b = blockIdx.x;
    const int tid = threadIdx.x;
    if (b < NB) {
        for (int w = tid; w < NHW; w += 1024) lh[w] = 0;
        if (b == 0 && tid == 0) *cursor = 0;   // alloc cursor for scan_cols_off
        __syncthreads();
        const int base = b * ECH;
        for (int k = tid; k < ECH; k += 1024) {
            int e = base + k;
            int r = erow[e];
            int sh = (r & 3) * 8;
            u32 old = atomicAdd(&lh[r >> 2], 1u << sh);
            lrank[e] = (u16)((old >> sh) & 0xffu);
        }
        __syncthreads();
        u32* hb = histw + b * NHW;
        for (int w = tid; w < NHW; w += 1024) hb[w] = lh[w];
    } else if (b < NB + 1563) {
        int i = (b - NB) * 1024 + tid;
        if (i < NN * D / 4) {
            float4 v = ((const float4*)x)[i];
            f16x4 o = {(f16)v.x, (f16)v.y, (f16)v.z, (f16)v.w};
            ((f16x4*)xf)[i] = o;
            u32 lo = __builtin_amdgcn_cvt_pk_fp8_f32(v.x, v.y, 0, false);
            u32 pk = __builtin_amdgcn_cvt_pk_fp8_f32(v.z, v.w, lo, true);
            ((u32*)xf8)[i] = pk;
        }
    } else {
        int wb = b - (NB + 1563);              // 0..23, 4 blocks per mat
        int mat = wb >> 2;
        const float* s; f16* d;
        switch (mat) {
            case 0: s = w0; d = d0; break; case 1: s = w1; d = d1; break;
            case 2: s = w2; d = d2; break; case 3: s = w3; d = d3; break;
            case 4: s = w4; d = d4; break; default: s = w5; d = d5; break;
        }
        int i = (wb & 3) * 1024 + tid;         // 0..4095 float4
        float4 v = ((const float4*)s)[i];
        f16x4 o = {(f16)v.x, (f16)v.y, (f16)v.z, (f16)v.w};
        ((f16x4*)d)[i] = o;
    }
}

// ---------------- fused column scan + segment allocation ----------------
__global__ __launch_bounds__(256) void scan_cols_off(
    const u32* __restrict__ histw, u16* __restrict__ start16,
    int* __restrict__ deg, int* __restrict__ cursor,
    int* __restrict__ offsets) {
    __shared__ int wsum[4];
    __shared__ int bbase;
    const int tid = threadIdx.x;
    const int w = tid >> 6, lane = tid & 63;
    const int n = blockIdx.x * 256 + tid;

    int s = 0;
    if (n < NN) {
        int sh = (n & 3) * 8;
        for (int b = 0; b < NB; ++b) {
            u32 wv = histw[b * NHW + (n >> 2)];
            start16[b * NN + n] = (u16)s;
            s += (int)((wv >> sh) & 0xffu);
        }
        deg[n] = s;
    }
    int v = s;
    int x = v;
#pragma unroll
    for (int m = 1; m < 64; m <<= 1) {
        int t = __shfl_up(x, m, 64);
        if (lane >= m) x += t;
    }
    if (lane == 63) wsum[w] = x;
    __syncthreads();
    if (w == 0) {
        int t = (lane < 4) ? wsum[lane] : 0;
#pragma unroll
        for (int m = 1; m < 4; m <<= 1) {
            int u = __shfl_up(t, m, 64);
            if (lane >= m) t += u;
        }
        if (lane < 4) wsum[lane] = t;
        if (lane == 3) bbase = atomicAdd(cursor, t);
    }
    __syncthreads();
    int excl = x - v + (w ? wsum[w - 1] : 0);
    if (n < NN) offsets[n] = bbase + excl;
}

__global__ __launch_bounds__(256) void fill_csr(
    const int* __restrict__ row, const int* __restrict__ col,
    const u16* __restrict__ lrank, const u16* __restrict__ start16,
    const int* __restrict__ offsets, u16* __restrict__ csr_col) {
    int i = blockIdx.x * 256 + threadIdx.x;   // < NE exactly (3125*256)
    int r = row[i];
    int b = i / ECH;
    int p = offsets[r] + (int)start16[b * NN + r] + (int)lrank[i];
    csr_col[p] = (u16)col[i];
}

// ---------------- fused layer: gather (round-7 geometry) + MFMA dual-GEMM ----
// Block = 16 nodes (3125 blocks x 256 thr). Each wave gathers 4 nodes
// SEQUENTIALLY with the proven shape (sub=lane>>4 edge slot, fl=lane&15
// feature octet, 16 edges in flight, csr preload + __shfl broadcast),
// normalizes, writes its rows into a 16x128 LDS agg tile. Then the 4 waves
// compute the 16x128 dual-GEMM output (wave w -> cols [w*32, w*32+32)):
// out = aggT@Wl^T + relu?(x)@Wr^T + b (+ x). Weight half-0 staging is issued
// BEFORE the gather so its latency hides. No aggb buffer, 1 launch per layer.
// fp8 out must ping-pong with fp8 in (other blocks still gathering).
#define WPAD 72    // half-K row stride: 64+8 f16
#define AP   136   // agg tile row stride: 128+8 f16

template<int RELU_X, int ADD_RES, int OUT_F32>
__global__ __launch_bounds__(256) void sage_layer(
    const u8* __restrict__ h8, const int* __restrict__ offsets,
    const int* __restrict__ degv, const u16* __restrict__ csr,
    const f16* __restrict__ xb,
    const f16* __restrict__ Wl, const f16* __restrict__ Wr,
    const float* __restrict__ bias, float* __restrict__ outf,
    f16* __restrict__ outh, u8* __restrict__ out8) {
    __shared__ f16 sW[2][128][WPAD];   // 36864 B (one K-half of both mats)
    __shared__ f16 aggT[16][AP];       // 4352 B

    const int tid  = threadIdx.x;
    const int wave = tid >> 6;
    const int lane = tid & 63;
    const int sub = lane >> 4, fl = lane & 15;
    const int mb = blockIdx.x * 16;    // block's 16 rows (exact: 3125*16=NN)

    // stage W K-half 0 (issued up front; completes under the gather)
#pragma unroll
    for (int it = 0; it < 8; ++it) {
        int idx = tid + it * 256;
        int mat = idx >> 10;
        int n   = (idx >> 3) & 127;
        int c   = idx & 7;
        const f16* W = mat ? Wr : Wl;
        f16x8 v = *(const f16x8*)(W + n * D + c * 8);
        *(f16x8*)&sW[mat][n][c * 8] = v;
    }

#define UNPACK_ADD(vv)                                                 \
    do {                                                               \
        f32x2 p;                                                       \
        p = __builtin_amdgcn_cvt_pk_f32_fp8((vv).x, false);            \
        acc[0] += p.x; acc[1] += p.y;                                  \
        p = __builtin_amdgcn_cvt_pk_f32_fp8((vv).x, true);             \
        acc[2] += p.x; acc[3] += p.y;                                  \
        p = __builtin_amdgcn_cvt_pk_f32_fp8((vv).y, false);            \
        acc[4] += p.x; acc[5] += p.y;                                  \
        p = __builtin_amdgcn_cvt_pk_f32_fp8((vv).y, true);             \
        acc[6] += p.x; acc[7] += p.y;                                  \
    } while (0)

    // gather phase: this wave's 4 nodes, sequential
    const u8* hp = h8 + fl * 8;
#pragma unroll 1
    for (int i = 0; i < 4; ++i) {
        int node = mb + wave * 4 + i;
        int s0  = offsets[node];
        int deg = degv[node];
        int cl = 0;
        if (lane < deg) cl = (int)csr[s0 + lane];   // coalesced preload

        float acc[8];
#pragma unroll
        for (int u = 0; u < 8; ++u) acc[u] = 0.f;

        int ng = (deg <= 64) ? deg : 64;
        int e = sub;
        for (int it = ng >> 4; it > 0; --it, e += 16) {
            int c0 = __shfl(cl, e, 64);
            int c1 = __shfl(cl, e + 4, 64);
            int c2 = __shfl(cl, e + 8, 64);
            int c3 = __shfl(cl, e + 12, 64);
            uint2 g0 = *(const uint2*)(hp + (size_t)c0 * D);
            uint2 g1 = *(const uint2*)(hp + (size_t)c1 * D);
            uint2 g2 = *(const uint2*)(hp + (size_t)c2 * D);
            uint2 g3 = *(const uint2*)(hp + (size_t)c3 * D);
            UNPACK_ADD(g0);
            UNPACK_ADD(g1);
            UNPACK_ADD(g2);
            UNPACK_ADD(g3);
        }
        if (ng & 8) {
            int c0 = __shfl(cl, e, 64);
            int c1 = __shfl(cl, e + 4, 64);
            uint2 g0 = *(const uint2*)(hp + (size_t)c0 * D);
            uint2 g1 = *(const uint2*)(hp + (size_t)c1 * D);
            UNPACK_ADD(g0);
            UNPACK_ADD(g1);
            e += 8;
        }
        if (ng & 4) {
            int c = __shfl(cl, e, 64);
            uint2 g = *(const uint2*)(hp + (size_t)c * D);
            UNPACK_ADD(g);
            e += 4;
        }
        {
            int r = ng & 3;
            if (r) {
                int ec = (e < ng) ? e : (ng - 1);   // keep shuffle convergent
                int c = __shfl(cl, ec, 64);
                if (sub < r) {
                    uint2 g = *(const uint2*)(hp + (size_t)c * D);
                    UNPACK_ADD(g);
                }
            }
        }
        if (deg > 64) {   // rare fallback past the preload window
            for (int jj = s0 + 64 + sub; jj < s0 + deg; jj += 4) {
                int c = (int)csr[jj];
                uint2 g = *(const uint2*)(hp + (size_t)c * D);
                UNPACK_ADD(g);
            }
        }

#pragma unroll
        for (int u = 0; u < 8; ++u) {
            acc[u] += __shfl_xor(acc[u], 16, 64);
            acc[u] += __shfl_xor(acc[u], 32, 64);
        }
        if (sub == 0) {
            float inv = 1.f / fmaxf((float)deg, 1.f);
            f16x8 o;
#pragma unroll
            for (int u = 0; u < 8; ++u) o[u] = (f16)(acc[u] * inv);
            *(f16x8*)&aggT[wave * 4 + i][fl * 8] = o;
        }
    }
#undef UNPACK_ADD

    __syncthreads();   // aggT complete + sW half-0 complete

    // MFMA phase: wave w computes output cols [w*32, w*32+32) for all 16 rows
    const int lm = fl, q = sub;
    const int nt0 = wave * 2;
    const f16* xrow = xb + (size_t)(mb + lm) * D + q * 8;
    f32x4 acc0 = (f32x4){0.f, 0.f, 0.f, 0.f};
    f32x4 acc1 = (f32x4){0.f, 0.f, 0.f, 0.f};

    {   // K-half 0 (ks = 0,1)
        f16x8 Aa0 = *(const f16x8*)&aggT[lm][q * 8];
        f16x8 Aa1 = *(const f16x8*)&aggT[lm][32 + q * 8];
        f16x8 Ax0 = *(const f16x8*)(xrow);
        f16x8 Ax1 = *(const f16x8*)(xrow + 32);
        if (RELU_X) {
#pragma unroll
            for (int u = 0; u < 8; ++u) {
                Ax0[u] = (Ax0[u] < (f16)0) ? (f16)0 : Ax0[u];
                Ax1[u] = (Ax1[u] < (f16)0) ? (f16)0 : Ax1[u];
            }
        }
#pragma unroll
        for (int j = 0; j < 2; ++j) {
            int n = (nt0 + j) * 16 + lm;
            f16x8 bl0 = *(const f16x8*)&sW[0][n][q * 8];
            f16x8 br0 = *(const f16x8*)&sW[1][n][q * 8];
            f16x8 bl1 = *(const f16x8*)&sW[0][n][32 + q * 8];
            f16x8 br1 = *(const f16x8*)&sW[1][n][32 + q * 8];
            f32x4 a = j ? acc1 : acc0;
            a = __builtin_amdgcn_mfma_f32_16x16x32_f16(Aa0, bl0, a, 0, 0, 0);
            a = __builtin_amdgcn_mfma_f32_16x16x32_f16(Ax0, br0, a, 0, 0, 0);
            a = __builtin_amdgcn_mfma_f32_16x16x32_f16(Aa1, bl1, a, 0, 0, 0);
            a = __builtin_amdgcn_mfma_f32_16x16x32_f16(Ax1, br1, a, 0, 0, 0);
            if (j) acc1 = a; else acc0 = a;
        }
    }

    __syncthreads();   // done reading sW half-0
    // stage W K-half 1
#pragma unroll
    for (int it = 0; it < 8; ++it) {
        int idx = tid + it * 256;
        int mat = idx >> 10;
        int n   = (idx >> 3) & 127;
        int c   = idx & 7;
        const f16* W = mat ? Wr : Wl;
        f16x8 v = *(const f16x8*)(W + n * D + 64 + c * 8);
        *(f16x8*)&sW[mat][n][c * 8] = v;
    }
    __syncthreads();

    {   // K-half 1 (ks = 2,3)
        f16x8 Aa2 = *(const f16x8*)&aggT[lm][64 + q * 8];
        f16x8 Aa3 = *(const f16x8*)&aggT[lm][96 + q * 8];
        f16x8 Ax2 = *(const f16x8*)(xrow + 64);
        f16x8 Ax3 = *(const f16x8*)(xrow + 96);
        if (RELU_X) {
#pragma unroll
            for (int u = 0; u < 8; ++u) {
                Ax2[u] = (Ax2[u] < (f16)0) ? (f16)0 : Ax2[u];
                Ax3[u] = (Ax3[u] < (f16)0) ? (f16)0 : Ax3[u];
            }
        }
#pragma unroll
        for (int j = 0; j < 2; ++j) {
            int n = (nt0 + j) * 16 + lm;
            f16x8 bl0 = *(const f16x8*)&sW[0][n][q * 8];
            f16x8 br0 = *(const f16x8*)&sW[1][n][q * 8];
            f16x8 bl1 = *(const f16x8*)&sW[0][n][32 + q * 8];
            f16x8 br1 = *(const f16x8*)&sW[1][n][32 + q * 8];
            f32x4 a = j ? acc1 : acc0;
            a = __builtin_amdgcn_mfma_f32_16x16x32_f16(Aa2, bl0, a, 0, 0, 0);
            a = __builtin_amdgcn_mfma_f32_16x16x32_f16(Ax2, br0, a, 0, 0, 0);
            a = __builtin_amdgcn_mfma_f32_16x16x32_f16(Aa3, bl1, a, 0, 0, 0);
            a = __builtin_amdgcn_mfma_f32_16x16x32_f16(Ax3, br1, a, 0, 0, 0);
            if (j) acc1 = a; else acc0 = a;
        }
    }

    // epilogue (rows owned by this block only -> in-place f16 safe)
#pragma unroll
    for (int j = 0; j < 2; ++j) {
        int n = (nt0 + j) * 16 + lm;
        float bval = bias[n];
        f32x4 a = j ? acc1 : acc0;
#pragma unroll
        for (int r = 0; r < 4; ++r) {
            int m = mb + q * 4 + r;
            size_t idx = (size_t)m * D + n;
            float v = a[r] + bval;
            if (ADD_RES) v += (float)xb[idx];
            if (OUT_F32) {
                outf[idx] = v;
            } else {
                outh[idx] = (f16)v;
                u32 t = __builtin_amdgcn_cvt_pk_fp8_f32(fmaxf(v, 0.f), 0.f, 0, false);
                out8[idx] = (u8)(t & 0xffu);
            }
        }
    }
}

// ---------------- launch ----------------

extern "C" void kernel_launch(void* const* d_in, const int* in_sizes, int n_in,
                              void* d_out, int out_size, void* d_ws, size_t ws_size,
                              hipStream_t stream) {
    const float* x    = (const float*)d_in[0];
    const int*   erow = (const int*)d_in[1];
    const int*   ecol = (const int*)d_in[2];
    const float* Wl0 = (const float*)d_in[3];
    const float* Wr0 = (const float*)d_in[4];
    const float* b0  = (const float*)d_in[5];
    const float* Wl1 = (const float*)d_in[6];
    const float* Wr1 = (const float*)d_in[7];
    const float* b1  = (const float*)d_in[8];
    const float* Wl2 = (const float*)d_in[9];
    const float* Wr2 = (const float*)d_in[10];
    const float* b2  = (const float*)d_in[11];

    char* ws = (char*)d_ws;
    size_t off = 0;
    auto carve = [&](size_t bytes) -> void* {
        void* p = ws + off;
        off = (off + bytes + 255) & ~(size_t)255;
        return p;
    };
    int*   deg     = (int*)carve((size_t)(NN + 1) * 4);   // deg[NN] = alloc cursor
    int*   offsets = (int*)carve((size_t)NN * 4);
    u32*   histw   = (u32*)carve((size_t)NB * NHW * 4);   // 3.2 MB
    u16*   start16 = (u16*)carve((size_t)NB * NN * 2);    // 6.4 MB
    u16*   lrank   = (u16*)carve((size_t)NE * 2);
    u16*   csr_col = (u16*)carve((size_t)NE * 2);
    f16*   xf      = (f16*)carve((size_t)NN * D * 2);
    f16*   x1      = (f16*)carve((size_t)NN * D * 2);
    u8*    xf8     = (u8*)carve((size_t)NN * D);
    u8*    x1f8    = (u8*)carve((size_t)NN * D);
    f16*   wl0 = (f16*)carve(D * D * 2); f16* wr0 = (f16*)carve(D * D * 2);
    f16*   wl1 = (f16*)carve(D * D * 2); f16* wr1 = (f16*)carve(D * D * 2);
    f16*   wl2 = (f16*)carve(D * D * 2); f16* wr2 = (f16*)carve(D * D * 2);
    (void)ws_size; (void)in_sizes; (void)n_in; (void)out_size;

    float* outp = (float*)d_out;

    // fused converts + LDS histograms
    prep_hist<<<NB + 1563 + 24, 1024, 0, stream>>>(
        x, xf, xf8, Wl0, Wr0, Wl1, Wr1, Wl2, Wr2,
        wl0, wr0, wl1, wr1, wl2, wr2, erow, histw, lrank, deg + NN);
    scan_cols_off<<<(NN + 255) / 256, 256, 0, stream>>>(histw, start16, deg,
                                                        deg + NN, offsets);
    fill_csr<<<NE / 256, 256, 0, stream>>>(erow, ecol, lrank, start16, offsets, csr_col);

    const int lgrid = NN / 16;   // 3125, exact

    // fp8 ping-pong: gather input != fp8 output (epilogue races other blocks)
    // layer 0: x1 = agg(xf8)@Wl0^T + xf@Wr0^T + b0; x1f8 = fp8(relu(x1))
    sage_layer<0, 0, 0><<<lgrid, 256, 0, stream>>>(
        xf8, offsets, deg, csr_col, xf, wl0, wr0, b0, nullptr, x1, x1f8);
    // layer 1: x1 += agg(x1f8)@Wl1^T + relu(x1)@Wr1^T + b1 (f16 in place)
    sage_layer<1, 1, 0><<<lgrid, 256, 0, stream>>>(
        x1f8, offsets, deg, csr_col, x1, wl1, wr1, b1, nullptr, x1, xf8);
    // layer 2: out = agg(xf8)@Wl2^T + relu(x1)@Wr2^T + b2 + x1 (fp32)
    sage_layer<1, 1, 1><<<lgrid, 256, 0, stream>>>(
        xf8, offsets, deg, csr_col, x1, wl2, wr2, b2, outp, nullptr, nullptr);
}

// Round 13
// 268.565 us; speedup vs baseline: 1.0817x; 1.0817x over previous
//
#include <hip/hip_runtime.h>

#define NN 50000
#define NE 800000
#define D  128

typedef _Float16 f16;
typedef _Float16 f16x4 __attribute__((ext_vector_type(4)));
typedef _Float16 f16x8 __attribute__((ext_vector_type(8)));
typedef float f32x4 __attribute__((ext_vector_type(4)));
typedef float f32x2 __attribute__((ext_vector_type(2)));
typedef unsigned short u16;
typedef unsigned int u32;
typedef unsigned int u32x2 __attribute__((ext_vector_type(2)));
typedef unsigned char u8;

#define NB   64      // histogram blocks
#define ECH  12500   // NE / NB
#define NHW  12500   // NN/4 u8-packed hist words per block

// ---------------- fused prep + histogram ----------------
// blocks [0,64): per-block LDS histogram of its 12500 edges (u8 x4 packed in
//   u32, 50 KB LDS). LDS atomicAdd return = local rank.
// [64, 64+1563): x -> xf (f16) + xf8 (fp8); [1627, 1651): 6 weight mats.
// The 64 hist blocks occupy 64 CUs while converts fill the rest.
__global__ __launch_bounds__(1024) void prep_hist(
    const float* __restrict__ x, f16* __restrict__ xf, u8* __restrict__ xf8,
    const float* w0, const float* w1, const float* w2,
    const float* w3, const float* w4, const float* w5,
    f16* d0, f16* d1, f16* d2, f16* d3, f16* d4, f16* d5,
    const int* __restrict__ erow, u32* __restrict__ histw,
    u16* __restrict__ lrank, int* __restrict__ cursor) {
    __shared__ u32 lh[NHW];   // 50 KB
    int b = blockIdx.x;
    const int tid = threadIdx.x;
    if (b < NB) {
        for (int w = tid; w < NHW; w += 1024) lh[w] = 0;
        if (b == 0 && tid == 0) *cursor = 0;   // alloc cursor for scan_cols_off
        __syncthreads();
        const int base = b * ECH;
        for (int k = tid; k < ECH; k += 1024) {
            int e = base + k;
            int r = erow[e];
            int sh = (r & 3) * 8;
            u32 old = atomicAdd(&lh[r >> 2], 1u << sh);
            lrank[e] = (u16)((old >> sh) & 0xffu);
        }
        __syncthreads();
        u32* hb = histw + b * NHW;
        for (int w = tid; w < NHW; w += 1024) hb[w] = lh[w];
    } else if (b < NB + 1563) {
        int i = (b - NB) * 1024 + tid;
        if (i < NN * D / 4) {
            float4 v = ((const float4*)x)[i];
            f16x4 o = {(f16)v.x, (f16)v.y, (f16)v.z, (f16)v.w};
            ((f16x4*)xf)[i] = o;
            u32 lo = __builtin_amdgcn_cvt_pk_fp8_f32(v.x, v.y, 0, false);
            u32 pk = __builtin_amdgcn_cvt_pk_fp8_f32(v.z, v.w, lo, true);
            ((u32*)xf8)[i] = pk;
        }
    } else {
        int wb = b - (NB + 1563);              // 0..23, 4 blocks per mat
        int mat = wb >> 2;
        const float* s; f16* d;
        switch (mat) {
            case 0: s = w0; d = d0; break; case 1: s = w1; d = d1; break;
            case 2: s = w2; d = d2; break; case 3: s = w3; d = d3; break;
            case 4: s = w4; d = d4; break; default: s = w5; d = d5; break;
        }
        int i = (wb & 3) * 1024 + tid;         // 0..4095 float4
        float4 v = ((const float4*)s)[i];
        f16x4 o = {(f16)v.x, (f16)v.y, (f16)v.z, (f16)v.w};
        ((f16x4*)d)[i] = o;
    }
}

// ---------------- fused column scan + segment allocation ----------------
__global__ __launch_bounds__(256) void scan_cols_off(
    const u32* __restrict__ histw, u16* __restrict__ start16,
    int* __restrict__ deg, int* __restrict__ cursor,
    int* __restrict__ offsets) {
    __shared__ int wsum[4];
    __shared__ int bbase;
    const int tid = threadIdx.x;
    const int w = tid >> 6, lane = tid & 63;
    const int n = blockIdx.x * 256 + tid;

    int s = 0;
    if (n < NN) {
        int sh = (n & 3) * 8;
        for (int b = 0; b < NB; ++b) {
            u32 wv = histw[b * NHW + (n >> 2)];
            start16[b * NN + n] = (u16)s;
            s += (int)((wv >> sh) & 0xffu);
        }
        deg[n] = s;
    }
    int v = s;
    int x = v;
#pragma unroll
    for (int m = 1; m < 64; m <<= 1) {
        int t = __shfl_up(x, m, 64);
        if (lane >= m) x += t;
    }
    if (lane == 63) wsum[w] = x;
    __syncthreads();
    if (w == 0) {
        int t = (lane < 4) ? wsum[lane] : 0;
#pragma unroll
        for (int m = 1; m < 4; m <<= 1) {
            int u = __shfl_up(t, m, 64);
            if (lane >= m) t += u;
        }
        if (lane < 4) wsum[lane] = t;
        if (lane == 3) bbase = atomicAdd(cursor, t);
    }
    __syncthreads();
    int excl = x - v + (w ? wsum[w - 1] : 0);
    if (n < NN) offsets[n] = bbase + excl;
}

__global__ __launch_bounds__(256) void fill_csr(
    const int* __restrict__ row, const int* __restrict__ col,
    const u16* __restrict__ lrank, const u16* __restrict__ start16,
    const int* __restrict__ offsets, u16* __restrict__ csr_col) {
    int i = blockIdx.x * 256 + threadIdx.x;   // < NE exactly (3125*256)
    int r = row[i];
    int b = i / ECH;
    int p = offsets[r] + (int)start16[b * NN + r] + (int)lrank[i];
    csr_col[p] = (u16)col[i];
}

// ---------------- mean aggregation (fp8 gather, fp32 accumulate) ----------------
// Round-7 geometry (empirically best): one wave per node, sub = lane>>4 edge
// slot, fl = lane&15 feature octet -> one contiguous 128B request per edge,
// 4 edges per wave instruction, 16 edges in flight; csr preload + __shfl.
// NEW (round 12): gather loads are NONTEMPORAL (bypass L1 allocation). Every
// gather misses L1 anyway (32KB vs 6.4MB random, ~0.5% hit) -- if the L1
// MSHR/fill path is the request-rate serializer, nt raises concurrency.
__global__ __launch_bounds__(256) void aggregate_f8(
    const u8* __restrict__ h8, const int* __restrict__ offsets,
    const int* __restrict__ degv, const u16* __restrict__ csr,
    f16* __restrict__ agg) {
    int node = blockIdx.x * 4 + (threadIdx.x >> 6);
    int lane = threadIdx.x & 63;
    int sub = lane >> 4, fl = lane & 15;
    int s0 = offsets[node];
    int deg = degv[node];

    int cl = 0;
    if (lane < deg) cl = (int)csr[s0 + lane];   // coalesced 128B preload

    float acc[8];
#pragma unroll
    for (int u = 0; u < 8; ++u) acc[u] = 0.f;

    const u8* hp = h8 + fl * 8;

#define GLOAD(cc) __builtin_nontemporal_load((const u32x2*)(hp + (size_t)(cc) * D))
#define UNPACK_ADD(vv)                                                 \
    do {                                                               \
        f32x2 p;                                                       \
        p = __builtin_amdgcn_cvt_pk_f32_fp8((vv).x, false);            \
        acc[0] += p.x; acc[1] += p.y;                                  \
        p = __builtin_amdgcn_cvt_pk_f32_fp8((vv).x, true);             \
        acc[2] += p.x; acc[3] += p.y;                                  \
        p = __builtin_amdgcn_cvt_pk_f32_fp8((vv).y, false);            \
        acc[4] += p.x; acc[5] += p.y;                                  \
        p = __builtin_amdgcn_cvt_pk_f32_fp8((vv).y, true);             \
        acc[6] += p.x; acc[7] += p.y;                                  \
    } while (0)

    int ng = (deg <= 64) ? deg : 64;   // edges served by the shuffle path
    int e = sub;
    for (int it = ng >> 4; it > 0; --it, e += 16) {
        int c0 = __shfl(cl, e, 64);
        int c1 = __shfl(cl, e + 4, 64);
        int c2 = __shfl(cl, e + 8, 64);
        int c3 = __shfl(cl, e + 12, 64);
        u32x2 g0 = GLOAD(c0);
        u32x2 g1 = GLOAD(c1);
        u32x2 g2 = GLOAD(c2);
        u32x2 g3 = GLOAD(c3);
        UNPACK_ADD(g0);
        UNPACK_ADD(g1);
        UNPACK_ADD(g2);
        UNPACK_ADD(g3);
    }
    if (ng & 8) {
        int c0 = __shfl(cl, e, 64);
        int c1 = __shfl(cl, e + 4, 64);
        u32x2 g0 = GLOAD(c0);
        u32x2 g1 = GLOAD(c1);
        UNPACK_ADD(g0);
        UNPACK_ADD(g1);
        e += 8;
    }
    if (ng & 4) {
        int c = __shfl(cl, e, 64);
        u32x2 g = GLOAD(c);
        UNPACK_ADD(g);
        e += 4;
    }
    {
        int r = ng & 3;
        if (r) {
            int ec = (e < ng) ? e : (ng - 1);   // keep shuffle convergent
            int c = __shfl(cl, ec, 64);
            if (sub < r) {
                u32x2 g = GLOAD(c);
                UNPACK_ADD(g);
            }
        }
    }
    if (deg > 64) {   // rare fallback: direct csr reads past the preload window
        for (int j = s0 + 64 + sub; j < s0 + deg; j += 4) {
            int c = (int)csr[j];
            u32x2 g = GLOAD(c);
            UNPACK_ADD(g);
        }
    }
#undef UNPACK_ADD
#undef GLOAD

    // reduce across the 4 edge slots (lanes l, l^16, l^32, l^48)
#pragma unroll
    for (int u = 0; u < 8; ++u) {
        acc[u] += __shfl_xor(acc[u], 16, 64);
        acc[u] += __shfl_xor(acc[u], 32, 64);
    }
    if (sub == 0) {
        float inv = 1.f / fmaxf((float)deg, 1.f);
        f16x8 o;
#pragma unroll
        for (int u = 0; u < 8; ++u) o[u] = (f16)(acc[u] * inv);
        *((f16x8*)(agg + (size_t)node * D) + fl) = o;
    }
}

// ---------------- MFMA dual-GEMM, LDS-staged weights ----------------
// out[m][n] = sum_k agg[m][k]*Wl[n][k] + relu?(x[m][k])*Wr[n][k] + b[n] (+ x[m][n])
// When !OUT_F32 also writes out8 = fp8(relu(out)) for the next layer's gather.
#define WPAD 72   // 64 + 8 f16 pad -> 144B row stride, <=2-way bank aliasing

template<int RELU_X, int ADD_RES, int OUT_F32>
__global__ __launch_bounds__(256, 4) void sage_gemm_mfma(
    const f16* __restrict__ aggb, const f16* __restrict__ xb,
    const f16* __restrict__ Wl, const f16* __restrict__ Wr,
    const float* __restrict__ bias, float* __restrict__ outf,
    f16* __restrict__ outh, u8* __restrict__ out8) {
    __shared__ f16 sW[2][128][WPAD];   // 36864 B

    const int tid  = threadIdx.x;
    const int wave = tid >> 6;
    const int lane = tid & 63;
    const int lm = lane & 15;
    const int q  = lane >> 4;
    const int mt = blockIdx.x * 64 + wave * 16;

    int row = mt + lm;
    int rclamp = (row < NN) ? row : NN - 1;

    // A fragments (full K), relu on x inline
    f16x8 Aa[4], Ax[4];
    const f16* arow = aggb + (size_t)rclamp * D + q * 8;
    const f16* xrow = xb  + (size_t)rclamp * D + q * 8;
#pragma unroll
    for (int ks = 0; ks < 4; ++ks) {
        Aa[ks] = *(const f16x8*)(arow + ks * 32);
        f16x8 v = *(const f16x8*)(xrow + ks * 32);
        if (RELU_X) {
#pragma unroll
            for (int u = 0; u < 8; ++u) v[u] = (v[u] < (f16)0) ? (f16)0 : v[u];
        }
        Ax[ks] = v;
    }

    f32x4 acc[8];
#pragma unroll
    for (int nt = 0; nt < 8; ++nt) acc[nt] = (f32x4){0.f, 0.f, 0.f, 0.f};

    for (int p = 0; p < 2; ++p) {
        __syncthreads();
        // stage Wl/Wr K-half: 2 mats x 128 n x 8 chunks of 16B = 2048 chunks
#pragma unroll
        for (int it = 0; it < 8; ++it) {
            int idx = tid + it * 256;
            int mat = idx >> 10;
            int n   = (idx >> 3) & 127;
            int c   = idx & 7;
            const f16* W = mat ? Wr : Wl;
            f16x8 v = *(const f16x8*)(W + n * D + p * 64 + c * 8);
            *(f16x8*)&sW[mat][n][c * 8] = v;
        }
        __syncthreads();

#pragma unroll
        for (int nt = 0; nt < 8; ++nt) {
#pragma unroll
            for (int k2 = 0; k2 < 2; ++k2) {
                f16x8 bl = *(const f16x8*)&sW[0][nt * 16 + lm][k2 * 32 + q * 8];
                acc[nt] = __builtin_amdgcn_mfma_f32_16x16x32_f16(Aa[p * 2 + k2], bl, acc[nt], 0, 0, 0);
                f16x8 br = *(const f16x8*)&sW[1][nt * 16 + lm][k2 * 32 + q * 8];
                acc[nt] = __builtin_amdgcn_mfma_f32_16x16x32_f16(Ax[p * 2 + k2], br, acc[nt], 0, 0, 0);
            }
        }
    }

    // epilogue: bias (+ f16 residual from xb). In-place outh==xb is safe:
    // each (m,n) is read & written by exactly one lane, rows owned by this wave.
#pragma unroll
    for (int nt = 0; nt < 8; ++nt) {
        int n = nt * 16 + lm;
        float bval = bias[n];
#pragma unroll
        for (int r = 0; r < 4; ++r) {
            int m = mt + q * 4 + r;
            if (m < NN) {
                size_t idx = (size_t)m * D + n;
                float v = acc[nt][r] + bval;
                if (ADD_RES) v += (float)xb[idx];
                if (OUT_F32) {
                    outf[idx] = v;
                } else {
                    outh[idx] = (f16)v;
                    u32 t = __builtin_amdgcn_cvt_pk_fp8_f32(fmaxf(v, 0.f), 0.f, 0, false);
                    out8[idx] = (u8)(t & 0xffu);
                }
            }
        }
    }
}

// ---------------- launch ----------------

extern "C" void kernel_launch(void* const* d_in, const int* in_sizes, int n_in,
                              void* d_out, int out_size, void* d_ws, size_t ws_size,
                              hipStream_t stream) {
    const float* x    = (const float*)d_in[0];
    const int*   erow = (const int*)d_in[1];
    const int*   ecol = (const int*)d_in[2];
    const float* Wl0 = (const float*)d_in[3];
    const float* Wr0 = (const float*)d_in[4];
    const float* b0  = (const float*)d_in[5];
    const float* Wl1 = (const float*)d_in[6];
    const float* Wr1 = (const float*)d_in[7];
    const float* b1  = (const float*)d_in[8];
    const float* Wl2 = (const float*)d_in[9];
    const float* Wr2 = (const float*)d_in[10];
    const float* b2  = (const float*)d_in[11];

    char* ws = (char*)d_ws;
    size_t off = 0;
    auto carve = [&](size_t bytes) -> void* {
        void* p = ws + off;
        off = (off + bytes + 255) & ~(size_t)255;
        return p;
    };
    int*   deg     = (int*)carve((size_t)(NN + 1) * 4);   // deg[NN] = alloc cursor
    int*   offsets = (int*)carve((size_t)NN * 4);
    u32*   histw   = (u32*)carve((size_t)NB * NHW * 4);   // 3.2 MB
    u16*   start16 = (u16*)carve((size_t)NB * NN * 2);    // 6.4 MB
    u16*   lrank   = (u16*)carve((size_t)NE * 2);
    u16*   csr_col = (u16*)carve((size_t)NE * 2);
    f16*   xf      = (f16*)carve((size_t)NN * D * 2);
    f16*   x1      = (f16*)carve((size_t)NN * D * 2);
    f16*   aggb    = (f16*)carve((size_t)NN * D * 2);
    u8*    xf8     = (u8*)carve((size_t)NN * D);
    u8*    x1f8    = (u8*)carve((size_t)NN * D);
    f16*   wl0 = (f16*)carve(D * D * 2); f16* wr0 = (f16*)carve(D * D * 2);
    f16*   wl1 = (f16*)carve(D * D * 2); f16* wr1 = (f16*)carve(D * D * 2);
    f16*   wl2 = (f16*)carve(D * D * 2); f16* wr2 = (f16*)carve(D * D * 2);
    (void)ws_size; (void)in_sizes; (void)n_in; (void)out_size;

    float* outp = (float*)d_out;

    // fused converts + LDS histograms (hist hides under convert streaming)
    prep_hist<<<NB + 1563 + 24, 1024, 0, stream>>>(
        x, xf, xf8, Wl0, Wr0, Wl1, Wr1, Wl2, Wr2,
        wl0, wr0, wl1, wr1, wl2, wr2, erow, histw, lrank, deg + NN);
    // column scan -> offsets; then CSR fill (0 global atomics anywhere)
    scan_cols_off<<<(NN + 255) / 256, 256, 0, stream>>>(histw, start16, deg,
                                                        deg + NN, offsets);
    fill_csr<<<NE / 256, 256, 0, stream>>>(erow, ecol, lrank, start16, offsets, csr_col);

    const int agrid = NN / 4;               // 12500, exact
    const int ggrid = (NN + 63) / 64;       // 782

    // layer 0: x1 = agg(x)@Wl0^T + x@Wr0^T + b0; x1f8 = fp8(relu(x1))
    aggregate_f8<<<agrid, 256, 0, stream>>>(xf8, offsets, deg, csr_col, aggb);
    sage_gemm_mfma<0, 0, 0><<<ggrid, 256, 0, stream>>>(aggb, xf, wl0, wr0, b0,
                                                       nullptr, x1, x1f8);
    // layer 1: x1 = agg(relu(x1))@Wl1^T + relu(x1)@Wr1^T + b1 + x1  (in place)
    aggregate_f8<<<agrid, 256, 0, stream>>>(x1f8, offsets, deg, csr_col, aggb);
    sage_gemm_mfma<1, 1, 0><<<ggrid, 256, 0, stream>>>(aggb, x1, wl1, wr1, b1,
                                                       nullptr, x1, x1f8);
    // layer 2: out = agg(relu(x1))@Wl2^T + relu(x1)@Wr2^T + b2 + x1  (fp32)
    aggregate_f8<<<agrid, 256, 0, stream>>>(x1f8, offsets, deg, csr_col, aggb);
    sage_gemm_mfma<1, 1, 1><<<ggrid, 256, 0, stream>>>(aggb, x1, wl2, wr2, b2,
                                                       outp, nullptr, nullptr);
}

// Round 14
// 243.423 us; speedup vs baseline: 1.1934x; 1.1033x over previous
//
#include <hip/hip_runtime.h>

#define NN 50000
#define NE 800000
#define D  128

typedef _Float16 f16;
typedef _Float16 f16x4 __attribute__((ext_vector_type(4)));
typedef _Float16 f16x8 __attribute__((ext_vector_type(8)));
typedef float f32x4 __attribute__((ext_vector_type(4)));
typedef float f32x2 __attribute__((ext_vector_type(2)));
typedef unsigned short u16;
typedef unsigned int u32;
typedef unsigned char u8;

#define NB   64      // histogram blocks
#define ECH  12500   // NE / NB
#define NHW  12500   // NN/4 u8-packed hist words per block

// ---------------- fused prep + histogram ----------------
// blocks [0,64): per-block LDS histogram of its 12500 edges (u8 x4 packed in
//   u32, 50 KB LDS). LDS atomicAdd return = local rank.
// [64, 64+1563): x -> xf (f16) + xf8 (fp8); [1627, 1651): 6 weight mats.
// The 64 hist blocks occupy 64 CUs while converts fill the rest.
__global__ __launch_bounds__(1024) void prep_hist(
    const float* __restrict__ x, f16* __restrict__ xf, u8* __restrict__ xf8,
    const float* w0, const float* w1, const float* w2,
    const float* w3, const float* w4, const float* w5,
    f16* d0, f16* d1, f16* d2, f16* d3, f16* d4, f16* d5,
    const int* __restrict__ erow, u32* __restrict__ histw,
    u16* __restrict__ lrank, int* __restrict__ cursor) {
    __shared__ u32 lh[NHW];   // 50 KB
    int b = blockIdx.x;
    const int tid = threadIdx.x;
    if (b < NB) {
        for (int w = tid; w < NHW; w += 1024) lh[w] = 0;
        if (b == 0 && tid == 0) *cursor = 0;   // alloc cursor for scan_cols_off
        __syncthreads();
        const int base = b * ECH;
        for (int k = tid; k < ECH; k += 1024) {
            int e = base + k;
            int r = erow[e];
            int sh = (r & 3) * 8;
            u32 old = atomicAdd(&lh[r >> 2], 1u << sh);
            lrank[e] = (u16)((old >> sh) & 0xffu);
        }
        __syncthreads();
        u32* hb = histw + b * NHW;
        for (int w = tid; w < NHW; w += 1024) hb[w] = lh[w];
    } else if (b < NB + 1563) {
        int i = (b - NB) * 1024 + tid;
        if (i < NN * D / 4) {
            float4 v = ((const float4*)x)[i];
            f16x4 o = {(f16)v.x, (f16)v.y, (f16)v.z, (f16)v.w};
            ((f16x4*)xf)[i] = o;
            u32 lo = __builtin_amdgcn_cvt_pk_fp8_f32(v.x, v.y, 0, false);
            u32 pk = __builtin_amdgcn_cvt_pk_fp8_f32(v.z, v.w, lo, true);
            ((u32*)xf8)[i] = pk;
        }
    } else {
        int wb = b - (NB + 1563);              // 0..23, 4 blocks per mat
        int mat = wb >> 2;
        const float* s; f16* d;
        switch (mat) {
            case 0: s = w0; d = d0; break; case 1: s = w1; d = d1; break;
            case 2: s = w2; d = d2; break; case 3: s = w3; d = d3; break;
            case 4: s = w4; d = d4; break; default: s = w5; d = d5; break;
        }
        int i = (wb & 3) * 1024 + tid;         // 0..4095 float4
        float4 v = ((const float4*)s)[i];
        f16x4 o = {(f16)v.x, (f16)v.y, (f16)v.z, (f16)v.w};
        ((f16x4*)d)[i] = o;
    }
}

// ---------------- fused column scan + segment allocation ----------------
__global__ __launch_bounds__(256) void scan_cols_off(
    const u32* __restrict__ histw, u16* __restrict__ start16,
    int* __restrict__ deg, int* __restrict__ cursor,
    int* __restrict__ offsets) {
    __shared__ int wsum[4];
    __shared__ int bbase;
    const int tid = threadIdx.x;
    const int w = tid >> 6, lane = tid & 63;
    const int n = blockIdx.x * 256 + tid;

    int s = 0;
    if (n < NN) {
        int sh = (n & 3) * 8;
        for (int b = 0; b < NB; ++b) {
            u32 wv = histw[b * NHW + (n >> 2)];
            start16[b * NN + n] = (u16)s;
            s += (int)((wv >> sh) & 0xffu);
        }
        deg[n] = s;
    }
    int v = s;
    int x = v;
#pragma unroll
    for (int m = 1; m < 64; m <<= 1) {
        int t = __shfl_up(x, m, 64);
        if (lane >= m) x += t;
    }
    if (lane == 63) wsum[w] = x;
    __syncthreads();
    if (w == 0) {
        int t = (lane < 4) ? wsum[lane] : 0;
#pragma unroll
        for (int m = 1; m < 4; m <<= 1) {
            int u = __shfl_up(t, m, 64);
            if (lane >= m) t += u;
        }
        if (lane < 4) wsum[lane] = t;
        if (lane == 3) bbase = atomicAdd(cursor, t);
    }
    __syncthreads();
    int excl = x - v + (w ? wsum[w - 1] : 0);
    if (n < NN) offsets[n] = bbase + excl;
}

__global__ __launch_bounds__(256) void fill_csr(
    const int* __restrict__ row, const int* __restrict__ col,
    const u16* __restrict__ lrank, const u16* __restrict__ start16,
    const int* __restrict__ offsets, u16* __restrict__ csr_col) {
    int i = blockIdx.x * 256 + threadIdx.x;   // < NE exactly (3125*256)
    int r = row[i];
    int b = i / ECH;
    int p = offsets[r] + (int)start16[b * NN + r] + (int)lrank[i];
    csr_col[p] = (u16)col[i];
}

// ---------------- mean aggregation (fp8 gather, fp32 accumulate) ----------------
// Round-7/10 geometry (empirically best of 6 probed variants): one wave per
// node, sub = lane>>4 edge slot, fl = lane&15 feature octet -> one contiguous
// 128B request per edge, 4 edges per wave instruction, 16 edges in flight;
// csr preload + __shfl broadcast. Plain cached loads (nt regressed: L2 reuse
// of the 6.4MB table is what keeps the request floor at ~32ns/request).
__global__ __launch_bounds__(256) void aggregate_f8(
    const u8* __restrict__ h8, const int* __restrict__ offsets,
    const int* __restrict__ degv, const u16* __restrict__ csr,
    f16* __restrict__ agg) {
    int node = blockIdx.x * 4 + (threadIdx.x >> 6);
    int lane = threadIdx.x & 63;
    int sub = lane >> 4, fl = lane & 15;
    int s0 = offsets[node];
    int deg = degv[node];

    int cl = 0;
    if (lane < deg) cl = (int)csr[s0 + lane];   // coalesced 128B preload

    float acc[8];
#pragma unroll
    for (int u = 0; u < 8; ++u) acc[u] = 0.f;

    const u8* hp = h8 + fl * 8;

#define UNPACK_ADD(vv)                                                 \
    do {                                                               \
        f32x2 p;                                                       \
        p = __builtin_amdgcn_cvt_pk_f32_fp8((vv).x, false);            \
        acc[0] += p.x; acc[1] += p.y;                                  \
        p = __builtin_amdgcn_cvt_pk_f32_fp8((vv).x, true);             \
        acc[2] += p.x; acc[3] += p.y;                                  \
        p = __builtin_amdgcn_cvt_pk_f32_fp8((vv).y, false);            \
        acc[4] += p.x; acc[5] += p.y;                                  \
        p = __builtin_amdgcn_cvt_pk_f32_fp8((vv).y, true);             \
        acc[6] += p.x; acc[7] += p.y;                                  \
    } while (0)

    int ng = (deg <= 64) ? deg : 64;   // edges served by the shuffle path
    int e = sub;
    for (int it = ng >> 4; it > 0; --it, e += 16) {
        int c0 = __shfl(cl, e, 64);
        int c1 = __shfl(cl, e + 4, 64);
        int c2 = __shfl(cl, e + 8, 64);
        int c3 = __shfl(cl, e + 12, 64);
        uint2 g0 = *(const uint2*)(hp + (size_t)c0 * D);
        uint2 g1 = *(const uint2*)(hp + (size_t)c1 * D);
        uint2 g2 = *(const uint2*)(hp + (size_t)c2 * D);
        uint2 g3 = *(const uint2*)(hp + (size_t)c3 * D);
        UNPACK_ADD(g0);
        UNPACK_ADD(g1);
        UNPACK_ADD(g2);
        UNPACK_ADD(g3);
    }
    if (ng & 8) {
        int c0 = __shfl(cl, e, 64);
        int c1 = __shfl(cl, e + 4, 64);
        uint2 g0 = *(const uint2*)(hp + (size_t)c0 * D);
        uint2 g1 = *(const uint2*)(hp + (size_t)c1 * D);
        UNPACK_ADD(g0);
        UNPACK_ADD(g1);
        e += 8;
    }
    if (ng & 4) {
        int c = __shfl(cl, e, 64);
        uint2 g = *(const uint2*)(hp + (size_t)c * D);
        UNPACK_ADD(g);
        e += 4;
    }
    {
        int r = ng & 3;
        if (r) {
            int ec = (e < ng) ? e : (ng - 1);   // keep shuffle convergent
            int c = __shfl(cl, ec, 64);
            if (sub < r) {
                uint2 g = *(const uint2*)(hp + (size_t)c * D);
                UNPACK_ADD(g);
            }
        }
    }
    if (deg > 64) {   // rare fallback: direct csr reads past the preload window
        for (int j = s0 + 64 + sub; j < s0 + deg; j += 4) {
            int c = (int)csr[j];
            uint2 g = *(const uint2*)(hp + (size_t)c * D);
            UNPACK_ADD(g);
        }
    }
#undef UNPACK_ADD

    // reduce across the 4 edge slots (lanes l, l^16, l^32, l^48)
#pragma unroll
    for (int u = 0; u < 8; ++u) {
        acc[u] += __shfl_xor(acc[u], 16, 64);
        acc[u] += __shfl_xor(acc[u], 32, 64);
    }
    if (sub == 0) {
        float inv = 1.f / fmaxf((float)deg, 1.f);
        f16x8 o;
#pragma unroll
        for (int u = 0; u < 8; ++u) o[u] = (f16)(acc[u] * inv);
        *((f16x8*)(agg + (size_t)node * D) + fl) = o;
    }
}

// ---------------- MFMA dual-GEMM, LDS-staged weights ----------------
// out[m][n] = sum_k agg[m][k]*Wl[n][k] + relu?(x[m][k])*Wr[n][k] + b[n] (+ x[m][n])
// When !OUT_F32 also writes out8 = fp8(relu(out)) for the next layer's gather.
#define WPAD 72   // 64 + 8 f16 pad -> 144B row stride, <=2-way bank aliasing

template<int RELU_X, int ADD_RES, int OUT_F32>
__global__ __launch_bounds__(256, 4) void sage_gemm_mfma(
    const f16* __restrict__ aggb, const f16* __restrict__ xb,
    const f16* __restrict__ Wl, const f16* __restrict__ Wr,
    const float* __restrict__ bias, float* __restrict__ outf,
    f16* __restrict__ outh, u8* __restrict__ out8) {
    __shared__ f16 sW[2][128][WPAD];   // 36864 B

    const int tid  = threadIdx.x;
    const int wave = tid >> 6;
    const int lane = tid & 63;
    const int lm = lane & 15;
    const int q  = lane >> 4;
    const int mt = blockIdx.x * 64 + wave * 16;

    int row = mt + lm;
    int rclamp = (row < NN) ? row : NN - 1;

    // A fragments (full K), relu on x inline
    f16x8 Aa[4], Ax[4];
    const f16* arow = aggb + (size_t)rclamp * D + q * 8;
    const f16* xrow = xb  + (size_t)rclamp * D + q * 8;
#pragma unroll
    for (int ks = 0; ks < 4; ++ks) {
        Aa[ks] = *(const f16x8*)(arow + ks * 32);
        f16x8 v = *(const f16x8*)(xrow + ks * 32);
        if (RELU_X) {
#pragma unroll
            for (int u = 0; u < 8; ++u) v[u] = (v[u] < (f16)0) ? (f16)0 : v[u];
        }
        Ax[ks] = v;
    }

    f32x4 acc[8];
#pragma unroll
    for (int nt = 0; nt < 8; ++nt) acc[nt] = (f32x4){0.f, 0.f, 0.f, 0.f};

    for (int p = 0; p < 2; ++p) {
        __syncthreads();
        // stage Wl/Wr K-half: 2 mats x 128 n x 8 chunks of 16B = 2048 chunks
#pragma unroll
        for (int it = 0; it < 8; ++it) {
            int idx = tid + it * 256;
            int mat = idx >> 10;
            int n   = (idx >> 3) & 127;
            int c   = idx & 7;
            const f16* W = mat ? Wr : Wl;
            f16x8 v = *(const f16x8*)(W + n * D + p * 64 + c * 8);
            *(f16x8*)&sW[mat][n][c * 8] = v;
        }
        __syncthreads();

#pragma unroll
        for (int nt = 0; nt < 8; ++nt) {
#pragma unroll
            for (int k2 = 0; k2 < 2; ++k2) {
                f16x8 bl = *(const f16x8*)&sW[0][nt * 16 + lm][k2 * 32 + q * 8];
                acc[nt] = __builtin_amdgcn_mfma_f32_16x16x32_f16(Aa[p * 2 + k2], bl, acc[nt], 0, 0, 0);
                f16x8 br = *(const f16x8*)&sW[1][nt * 16 + lm][k2 * 32 + q * 8];
                acc[nt] = __builtin_amdgcn_mfma_f32_16x16x32_f16(Ax[p * 2 + k2], br, acc[nt], 0, 0, 0);
            }
        }
    }

    // epilogue: bias (+ f16 residual from xb). In-place outh==xb is safe:
    // each (m,n) is read & written by exactly one lane, rows owned by this wave.
#pragma unroll
    for (int nt = 0; nt < 8; ++nt) {
        int n = nt * 16 + lm;
        float bval = bias[n];
#pragma unroll
        for (int r = 0; r < 4; ++r) {
            int m = mt + q * 4 + r;
            if (m < NN) {
                size_t idx = (size_t)m * D + n;
                float v = acc[nt][r] + bval;
                if (ADD_RES) v += (float)xb[idx];
                if (OUT_F32) {
                    outf[idx] = v;
                } else {
                    outh[idx] = (f16)v;
                    u32 t = __builtin_amdgcn_cvt_pk_fp8_f32(fmaxf(v, 0.f), 0.f, 0, false);
                    out8[idx] = (u8)(t & 0xffu);
                }
            }
        }
    }
}

// ---------------- launch ----------------

extern "C" void kernel_launch(void* const* d_in, const int* in_sizes, int n_in,
                              void* d_out, int out_size, void* d_ws, size_t ws_size,
                              hipStream_t stream) {
    const float* x    = (const float*)d_in[0];
    const int*   erow = (const int*)d_in[1];
    const int*   ecol = (const int*)d_in[2];
    const float* Wl0 = (const float*)d_in[3];
    const float* Wr0 = (const float*)d_in[4];
    const float* b0  = (const float*)d_in[5];
    const float* Wl1 = (const float*)d_in[6];
    const float* Wr1 = (const float*)d_in[7];
    const float* b1  = (const float*)d_in[8];
    const float* Wl2 = (const float*)d_in[9];
    const float* Wr2 = (const float*)d_in[10];
    const float* b2  = (const float*)d_in[11];

    char* ws = (char*)d_ws;
    size_t off = 0;
    auto carve = [&](size_t bytes) -> void* {
        void* p = ws + off;
        off = (off + bytes + 255) & ~(size_t)255;
        return p;
    };
    int*   deg     = (int*)carve((size_t)(NN + 1) * 4);   // deg[NN] = alloc cursor
    int*   offsets = (int*)carve((size_t)NN * 4);
    u32*   histw   = (u32*)carve((size_t)NB * NHW * 4);   // 3.2 MB
    u16*   start16 = (u16*)carve((size_t)NB * NN * 2);    // 6.4 MB
    u16*   lrank   = (u16*)carve((size_t)NE * 2);
    u16*   csr_col = (u16*)carve((size_t)NE * 2);
    f16*   xf      = (f16*)carve((size_t)NN * D * 2);
    f16*   x1      = (f16*)carve((size_t)NN * D * 2);
    f16*   aggb    = (f16*)carve((size_t)NN * D * 2);
    u8*    xf8     = (u8*)carve((size_t)NN * D);
    u8*    x1f8    = (u8*)carve((size_t)NN * D);
    f16*   wl0 = (f16*)carve(D * D * 2); f16* wr0 = (f16*)carve(D * D * 2);
    f16*   wl1 = (f16*)carve(D * D * 2); f16* wr1 = (f16*)carve(D * D * 2);
    f16*   wl2 = (f16*)carve(D * D * 2); f16* wr2 = (f16*)carve(D * D * 2);
    (void)ws_size; (void)in_sizes; (void)n_in; (void)out_size;

    float* outp = (float*)d_out;

    // fused converts + LDS histograms (hist hides under convert streaming)
    prep_hist<<<NB + 1563 + 24, 1024, 0, stream>>>(
        x, xf, xf8, Wl0, Wr0, Wl1, Wr1, Wl2, Wr2,
        wl0, wr0, wl1, wr1, wl2, wr2, erow, histw, lrank, deg + NN);
    // column scan -> offsets; then CSR fill (0 global atomics anywhere)
    scan_cols_off<<<(NN + 255) / 256, 256, 0, stream>>>(histw, start16, deg,
                                                        deg + NN, offsets);
    fill_csr<<<NE / 256, 256, 0, stream>>>(erow, ecol, lrank, start16, offsets, csr_col);

    const int agrid = NN / 4;               // 12500, exact
    const int ggrid = (NN + 63) / 64;       // 782

    // layer 0: x1 = agg(x)@Wl0^T + x@Wr0^T + b0; x1f8 = fp8(relu(x1))
    aggregate_f8<<<agrid, 256, 0, stream>>>(xf8, offsets, deg, csr_col, aggb);
    sage_gemm_mfma<0, 0, 0><<<ggrid, 256, 0, stream>>>(aggb, xf, wl0, wr0, b0,
                                                       nullptr, x1, x1f8);
    // layer 1: x1 = agg(relu(x1))@Wl1^T + relu(x1)@Wr1^T + b1 + x1  (in place)
    aggregate_f8<<<agrid, 256, 0, stream>>>(x1f8, offsets, deg, csr_col, aggb);
    sage_gemm_mfma<1, 1, 0><<<ggrid, 256, 0, stream>>>(aggb, x1, wl1, wr1, b1,
                                                       nullptr, x1, x1f8);
    // layer 2: out = agg(relu(x1))@Wl2^T + relu(x1)@Wr2^T + b2 + x1  (fp32)
    aggregate_f8<<<agrid, 256, 0, stream>>>(x1f8, offsets, deg, csr_col, aggb);
    sage_gemm_mfma<1, 1, 1><<<ggrid, 256, 0, stream>>>(aggb, x1, wl2, wr2, b2,
                                                       outp, nullptr, nullptr);
}